// Round 5
// baseline (1441.572 us; speedup 1.0000x reference)
//
#include <hip/hip_runtime.h>

#define BN_EPS 1e-3f

typedef __attribute__((ext_vector_type(8))) short short8;
typedef __attribute__((ext_vector_type(4))) float float4v;

#define NREP 16  // BN stat replicas (atomic contention spread)

__device__ __forceinline__ short f2bf(float f) {
    unsigned u = __float_as_uint(f);
    unsigned r = (u + 0x7FFFu + ((u >> 16) & 1u)) >> 16;
    return (short)r;
}

// ---------------- small utility kernels ----------------

__global__ __launch_bounds__(256) void zero_kernel(float* p, int n) {
    int i = blockIdx.x * 256 + threadIdx.x;
    if (i < n) p[i] = 0.f;
}

__global__ __launch_bounds__(256) void copy_kernel(const float* __restrict__ in,
                                                   float* __restrict__ out, int n) {
    int i = blockIdx.x * 256 + threadIdx.x;
    if (i < n) out[i] = in[i];
}

// coords rows are (b, z, y, x); xyz = (x,y,z) * (voxel*stride) + (0,-40,-3)
__global__ __launch_bounds__(256) void xyz_kernel(const int* __restrict__ coords,
                                                  float* __restrict__ out, int N,
                                                  float sx, float sy, float sz) {
    int n = blockIdx.x * 256 + threadIdx.x;
    if (n >= N) return;
    int4 c = ((const int4*)coords)[n];  // x=b, y=z, z=y, w=x
    out[n * 3 + 0] = c.w * sx;
    out[n * 3 + 1] = c.z * sy - 40.0f;
    out[n * 3 + 2] = c.y * sz - 3.0f;
}

// f0 (N x 4 fp32) -> bf16 padded (N x 32)
__global__ __launch_bounds__(256) void convert_f0(const float* __restrict__ f,
                                                  short* __restrict__ dst, int N) {
    int i = blockIdx.x * 256 + threadIdx.x;
    if (i >= N * 32) return;
    int c = i & 31, n = i >> 5;
    dst[i] = (c < 4) ? f2bf(f[n * 4 + c]) : (short)0;
}

// ---------------- all-layer weight prep: W [K][CIN][COUT] fp32 -> Wt [K][COUT][CHP] bf16 ----
struct PrepAll {
    const float* src[14];
    short* dst[14];
    int K[14];
    int CI[14];
    int CO[14];
    int CHP[14];
    int cum[15];
};

__global__ __launch_bounds__(256) void prep_all_kernel(PrepAll d) {
    int i = blockIdx.x * 256 + threadIdx.x;
    if (i >= d.cum[14]) return;
    int l = 0;
    while (l < 13 && i >= d.cum[l + 1]) ++l;
    int j = i - d.cum[l];
    int chp = d.CHP[l];
    int ci = j % chp;
    int co = (j / chp) % d.CO[l];
    int k = j / (chp * d.CO[l]);
    float v = (ci < d.CI[l]) ? d.src[l][((size_t)k * d.CI[l] + ci) * d.CO[l] + co] : 0.f;
    d.dst[l][j] = f2bf(v);
}

// ---------------- MFMA sparse conv, 1 wave/block, 16 rows x (CT*16) cols ----------------
// feat: bf16 [Nin][CHP]; Wt: bf16 [K][COUT][CHP]; rb: [K][N] (-1 = none)
// Fully unrolled K (template), explicit register double-buffering, all rulebook
// indices preloaded. __launch_bounds__(64,4): 128-VGPR budget -> NO scratch spill
// (default budget was ~64 VGPRs -> spilled the whole pipeline; R4 FETCH=54MB was spills).
// BN sum/sumsq fused, atomics into NREP replicas.
template <int CH, int CT, int COUT, int K>
__global__ __launch_bounds__(64, 4) void sconv_mfma(const short* __restrict__ feat,
                                                    const int* __restrict__ rb,
                                                    const short* __restrict__ Wt,
                                                    float* __restrict__ out,
                                                    float* __restrict__ stats, int N) {
    constexpr int CHP = CH * 32;
    const int lane = threadIdx.x;
    const int quad = lane >> 4;
    const int l16 = lane & 15;
    const int m0 = blockIdx.x * 16;
    const int row = m0 + l16;
    const int rowc = (row < N - 1) ? row : (N - 1);
    const int colbase = blockIdx.y * (CT * 16);
    const bool rvalid = (row < N);

    // preload all rulebook indices for this wave's 16 rows
    int idx[K];
#pragma unroll
    for (int k = 0; k < K; ++k) idx[k] = rb[(size_t)k * N + rowc];

    const short* fquad = feat + quad * 8;
    const short* wbase = Wt + (size_t)(colbase + l16) * CHP + quad * 8;

    short8 a[3][CH];      // depth-2 prefetch ring for gathered A rows
    short8 b[2][CH][CT];  // depth-1 double buffer for weights

    auto loadA = [&](short8(&dst)[CH], int k) {
        int ix = idx[k];
        bool v = rvalid && (ix >= 0);
        int cix = ix < 0 ? 0 : ix;
        const short* p = fquad + (size_t)cix * CHP;
#pragma unroll
        for (int c = 0; c < CH; ++c) {
            short8 t = *(const short8*)(p + c * 32);
            dst[c] = v ? t : (short8)0;
        }
    };
    auto loadB = [&](short8(&dst)[CH][CT], int k) {
        const short* p = wbase + (size_t)k * COUT * CHP;
#pragma unroll
        for (int t = 0; t < CT; ++t)
#pragma unroll
            for (int c = 0; c < CH; ++c)
                dst[c][t] = *(const short8*)(p + (size_t)t * 16 * CHP + c * 32);
    };

    float4v acc[CT];
#pragma unroll
    for (int t = 0; t < CT; ++t) acc[t] = (float4v)0.f;

    loadA(a[0], 0);
    if constexpr (K > 1) loadA(a[1], 1);
    loadB(b[0], 0);

#pragma unroll
    for (int k = 0; k < K; ++k) {
        if (k + 2 < K) loadA(a[(k + 2) % 3], k + 2);
        if (k + 1 < K) loadB(b[(k + 1) & 1], k + 1);
#pragma unroll
        for (int c = 0; c < CH; ++c)
#pragma unroll
            for (int t = 0; t < CT; ++t)
                acc[t] = __builtin_amdgcn_mfma_f32_16x16x32_bf16(a[k % 3][c], b[k & 1][c][t],
                                                                 acc[t], 0, 0, 0);
    }

    // D layout: col = lane&15, row = quad*4 + reg
    float* st = stats + (size_t)(blockIdx.x & (NREP - 1)) * 128;
#pragma unroll
    for (int t = 0; t < CT; ++t) {
        int col = colbase + t * 16 + l16;
#pragma unroll
        for (int r = 0; r < 4; ++r) {
            int orow = m0 + quad * 4 + r;
            if (orow < N) out[(size_t)orow * COUT + col] = acc[t][r];
        }
        // fused BN stats (rows >= N contributed exact zeros)
        float s = acc[t][0] + acc[t][1] + acc[t][2] + acc[t][3];
        float ss = acc[t][0] * acc[t][0] + acc[t][1] * acc[t][1] + acc[t][2] * acc[t][2] +
                   acc[t][3] * acc[t][3];
        s += __shfl_xor(s, 16);
        s += __shfl_xor(s, 32);
        ss += __shfl_xor(ss, 16);
        ss += __shfl_xor(ss, 32);
        if (lane < 16) {
            atomicAdd(&st[col], s);
            atomicAdd(&st[64 + col], ss);
        }
    }
}

// ---------------- BN apply + ReLU; replica-reduce in LDS prologue ----------------
// writes bf16 (padded to CHPN) for next layer and/or fp32 output
template <int COUT, int CHPN, bool F32OUT, bool BFOUT>
__global__ __launch_bounds__(256) void bn_apply(const float* __restrict__ x,
                                                const float* __restrict__ stats,
                                                const float* __restrict__ g,
                                                const float* __restrict__ b,
                                                float* __restrict__ fout,
                                                short* __restrict__ bfout, int N) {
    constexpr int CW = BFOUT ? CHPN : COUT;
    __shared__ float ssc[COUT];
    __shared__ float ssh[COUT];
    int tid = threadIdx.x;
    if (tid < COUT) {
        float s = 0.f, q = 0.f;
#pragma unroll
        for (int r = 0; r < NREP; ++r) {
            s += stats[r * 128 + tid];
            q += stats[r * 128 + 64 + tid];
        }
        float inv = 1.0f / (float)N;
        float m = s * inv;
        float v = q * inv - m * m;
        float sc = g[tid] / sqrtf(v + BN_EPS);
        ssc[tid] = sc;
        ssh[tid] = b[tid] - m * sc;
    }
    __syncthreads();
    long i = (long)blockIdx.x * 256 + tid;
    if (i >= (long)N * CW) return;
    int c = (int)(i % CW);
    long n = i / CW;
    float y = 0.f;
    if (c < COUT) {
        y = fmaxf(x[n * COUT + c] * ssc[c] + ssh[c], 0.f);
        if (F32OUT) fout[n * COUT + c] = y;
    }
    if (BFOUT) bfout[n * CHPN + c] = f2bf(y);
}

// ---------------- host helpers ----------------

template <int CH, int CT, int COUT, int K>
static void conv(const short* fin, const int* rb, const short* wt, float* preact, float* stats,
                 int N, hipStream_t stream) {
    dim3 grid((N + 15) / 16, COUT / (CT * 16));
    hipLaunchKernelGGL((sconv_mfma<CH, CT, COUT, K>), grid, dim3(64), 0, stream, fin, rb, wt,
                       preact, stats, N);
}

template <int COUT, int CHPN, bool F32OUT, bool BFOUT>
static void apply(const float* preact, const float* stats, const float* g, const float* b,
                  float* fout, short* bfout, int N, hipStream_t stream) {
    constexpr int CW = BFOUT ? CHPN : COUT;
    int blocks = (int)(((long)N * CW + 255) / 256);
    hipLaunchKernelGGL((bn_apply<COUT, CHPN, F32OUT, BFOUT>), dim3(blocks), dim3(256), 0, stream,
                       preact, stats, g, b, fout, bfout, N);
}

extern "C" void kernel_launch(void* const* d_in, const int* in_sizes, int n_in, void* d_out,
                              int out_size, void* d_ws, size_t ws_size, hipStream_t stream) {
    const float* features = (const float*)d_in[0];
    const float* W[14];
    const float* G[14];
    const float* Bb[14];
    for (int i = 0; i < 14; ++i) {
        W[i] = (const float*)d_in[1 + 3 * i];
        G[i] = (const float*)d_in[2 + 3 * i];
        Bb[i] = (const float*)d_in[3 + 3 * i];
    }
    const int* coords0 = (const int*)d_in[43];
    const int* coords1 = (const int*)d_in[44];
    const int* coords2 = (const int*)d_in[45];
    const int* coords3 = (const int*)d_in[46];
    const int* rb0 = (const int*)d_in[47];
    const int* rbc1 = (const int*)d_in[48];
    const int* rb1 = (const int*)d_in[49];
    const int* rbc2 = (const int*)d_in[50];
    const int* rb2 = (const int*)d_in[51];
    const int* rbc3 = (const int*)d_in[52];
    const int* rb3 = (const int*)d_in[53];
    const int* rbc4 = (const int*)d_in[54];

    const int N0 = in_sizes[0] / 4;
    const int N1 = in_sizes[44] / 4;
    const int N2 = in_sizes[45] / 4;
    const int N3 = in_sizes[46] / 4;
    const int N4 = in_sizes[54] / 3;

    float* out = (float*)d_out;
    long off = 0;
    float* xyz0 = out + off; off += (long)N0 * 3;
    float* f0   = out + off; off += (long)N0 * 4;
    float* xyz1 = out + off; off += (long)N1 * 3;
    float* f1   = out + off; off += (long)N1 * 32;
    float* xyz2 = out + off; off += (long)N2 * 3;
    float* f2   = out + off; off += (long)N2 * 64;
    float* xyz3 = out + off; off += (long)N3 * 3;
    float* f3   = out + off; off += (long)N3 * 64;
    float* f4   = out + off;

    long maxN = N0;
    if (N1 > maxN) maxN = N1;
    if (N2 > maxN) maxN = N2;
    if (N3 > maxN) maxN = N3;
    if (N4 > maxN) maxN = N4;

    // workspace layout
    float* preact = (float*)d_ws;                         // maxN*64 fp32
    float* statsBase = preact + (size_t)maxN * 64;        // 14 * NREP * 128 fp32
    short* bfA = (short*)(statsBase + 14 * NREP * 128);   // maxN*64 bf16
    short* bfB = bfA + (size_t)maxN * 64;                 // maxN*64 bf16
    short* wtBase = bfB + (size_t)maxN * 64;              // transposed bf16 weights

    static const int KK[14] = {27, 27, 27, 27, 27, 27, 27, 27, 27, 27, 27, 27, 27, 3};
    static const int CI[14] = {4, 16, 16, 32, 32, 32, 64, 64, 64, 64, 64, 64, 64, 64};
    static const int CO[14] = {16, 16, 32, 32, 32, 64, 64, 64, 64, 64, 64, 64, 64, 64};
    short* WT[14];
    PrepAll pd;
    {
        size_t o = 0;
        int cum = 0;
        for (int l = 0; l < 14; ++l) {
            WT[l] = wtBase + o;
            int chp = CI[l] <= 32 ? 32 : 64;
            pd.src[l] = W[l];
            pd.dst[l] = WT[l];
            pd.K[l] = KK[l];
            pd.CI[l] = CI[l];
            pd.CO[l] = CO[l];
            pd.CHP[l] = chp;
            pd.cum[l] = cum;
            cum += KK[l] * CO[l] * chp;
            o += (size_t)KK[l] * CO[l] * chp;
        }
        pd.cum[14] = cum;
    }

    // zero BN stat slots
    int nstats = 14 * NREP * 128;
    hipLaunchKernelGGL(zero_kernel, dim3((nstats + 255) / 256), dim3(256), 0, stream, statsBase,
                       nstats);

    // prep all weights in one launch
    hipLaunchKernelGGL(prep_all_kernel, dim3((pd.cum[14] + 255) / 256), dim3(256), 0, stream, pd);

    // passthrough outputs
    hipLaunchKernelGGL(copy_kernel, dim3((N0 * 4 + 255) / 256), dim3(256), 0, stream, features, f0,
                       N0 * 4);
    hipLaunchKernelGGL(xyz_kernel, dim3((N0 + 255) / 256), dim3(256), 0, stream, coords0, xyz0, N0,
                       0.05f, 0.05f, 0.1f);
    hipLaunchKernelGGL(xyz_kernel, dim3((N1 + 255) / 256), dim3(256), 0, stream, coords1, xyz1, N1,
                       0.1f, 0.1f, 0.2f);
    hipLaunchKernelGGL(xyz_kernel, dim3((N2 + 255) / 256), dim3(256), 0, stream, coords2, xyz2, N2,
                       0.2f, 0.2f, 0.4f);
    hipLaunchKernelGGL(xyz_kernel, dim3((N3 + 255) / 256), dim3(256), 0, stream, coords3, xyz3, N3,
                       0.4f, 0.4f, 0.8f);

    // f0 -> bf16 padded
    hipLaunchKernelGGL(convert_f0, dim3((N0 * 32 + 255) / 256), dim3(256), 0, stream, features,
                       bfA, N0);

    float* st = statsBase;
#define STAT(l) (st + (size_t)(l)*NREP * 128)

    // stage 1
    conv<1, 1, 16, 27>(bfA, rb0, WT[0], preact, STAT(0), N0, stream);
    apply<16, 32, false, true>(preact, STAT(0), G[0], Bb[0], nullptr, bfB, N0, stream);
    conv<1, 1, 16, 27>(bfB, rb0, WT[1], preact, STAT(1), N0, stream);
    apply<16, 32, false, true>(preact, STAT(1), G[1], Bb[1], nullptr, bfA, N0, stream);
    conv<1, 2, 32, 27>(bfA, rbc1, WT[2], preact, STAT(2), N1, stream);
    apply<32, 32, true, true>(preact, STAT(2), G[2], Bb[2], f1, bfB, N1, stream);
    // stage 2
    conv<1, 2, 32, 27>(bfB, rb1, WT[3], preact, STAT(3), N1, stream);
    apply<32, 32, false, true>(preact, STAT(3), G[3], Bb[3], nullptr, bfA, N1, stream);
    conv<1, 2, 32, 27>(bfA, rb1, WT[4], preact, STAT(4), N1, stream);
    apply<32, 32, false, true>(preact, STAT(4), G[4], Bb[4], nullptr, bfB, N1, stream);
    conv<1, 2, 64, 27>(bfB, rbc2, WT[5], preact, STAT(5), N2, stream);
    apply<64, 64, true, true>(preact, STAT(5), G[5], Bb[5], f2, bfA, N2, stream);
    // stage 3
    conv<2, 2, 64, 27>(bfA, rb2, WT[6], preact, STAT(6), N2, stream);
    apply<64, 64, false, true>(preact, STAT(6), G[6], Bb[6], nullptr, bfB, N2, stream);
    conv<2, 2, 64, 27>(bfB, rb2, WT[7], preact, STAT(7), N2, stream);
    apply<64, 64, false, true>(preact, STAT(7), G[7], Bb[7], nullptr, bfA, N2, stream);
    conv<2, 2, 64, 27>(bfA, rb2, WT[8], preact, STAT(8), N2, stream);
    apply<64, 64, false, true>(preact, STAT(8), G[8], Bb[8], nullptr, bfB, N2, stream);
    conv<2, 2, 64, 27>(bfB, rbc3, WT[9], preact, STAT(9), N3, stream);
    apply<64, 64, true, true>(preact, STAT(9), G[9], Bb[9], f3, bfA, N3, stream);
    // stage 4
    conv<2, 2, 64, 27>(bfA, rb3, WT[10], preact, STAT(10), N3, stream);
    apply<64, 64, false, true>(preact, STAT(10), G[10], Bb[10], nullptr, bfB, N3, stream);
    conv<2, 2, 64, 27>(bfB, rb3, WT[11], preact, STAT(11), N3, stream);
    apply<64, 64, false, true>(preact, STAT(11), G[11], Bb[11], nullptr, bfA, N3, stream);
    conv<2, 2, 64, 27>(bfA, rb3, WT[12], preact, STAT(12), N3, stream);
    apply<64, 64, false, true>(preact, STAT(12), G[12], Bb[12], nullptr, bfB, N3, stream);
    conv<2, 2, 64, 3>(bfB, rbc4, WT[13], preact, STAT(13), N4, stream);
    apply<64, 64, true, false>(preact, STAT(13), G[13], Bb[13], f4, nullptr, N4, stream);
#undef STAT
}